// Round 9
// baseline (197.496 us; speedup 1.0000x reference)
//
#include <hip/hip_runtime.h>
#include <hip/hip_bf16.h>

typedef __bf16 bf16x8 __attribute__((ext_vector_type(8)));
typedef float f32x4 __attribute__((ext_vector_type(4)));

static constexpr int NN = 4096;   // nodes
static constexpr int FE = 64;     // features
static constexpr int NH = 8;      // heads
#define LOG2E 1.44269504088896340736f

#if __has_builtin(__builtin_amdgcn_exp2f)
#define EXP2F(x) __builtin_amdgcn_exp2f(x)
#else
#define EXP2F(x) exp2f(x)
#endif

// ------------------------------------------------------------------
// Kernel 1: ltg = graph @ W[h]  (fp32), store ltgT (feature-major bf16),
//           s~ = (ltg . a_src)*log2e, d~ = (ltg . a_dst)*log2e
// grid (NN/64, NH), 256 threads   [unchanged]
// ------------------------------------------------------------------
__global__ __launch_bounds__(256) void gat_k1(
    const float* __restrict__ graph, const float* __restrict__ W,
    const float* __restrict__ a, ushort* __restrict__ ltgT,
    float* __restrict__ st, float* __restrict__ dt)
{
  const int h  = blockIdx.y;
  const int n0 = blockIdx.x * 64;
  const int t  = threadIdx.x;

  __shared__ float  Wl[64 * 68];   // Wl[f][k], padded
  __shared__ float  gT[64 * 68];   // gT[f][n], padded (graph transposed)
  __shared__ ushort lt[64 * 64];   // lt[k][n] bf16 staging for coalesced out

  const float* Wh = W + h * FE * FE;
  const int fr = t >> 2;           // row 0..63
  const int qc = (t & 3) * 16;     // col chunk
  #pragma unroll
  for (int e = 0; e < 4; e++) {
    float4 wv = *(const float4*)(Wh + fr * FE + qc + e * 4);
    *(float4*)(&Wl[fr * 68 + qc + e * 4]) = wv;
    float4 gv = *(const float4*)(graph + (n0 + fr) * FE + qc + e * 4);
    gT[(qc + e * 4 + 0) * 68 + fr] = gv.x;
    gT[(qc + e * 4 + 1) * 68 + fr] = gv.y;
    gT[(qc + e * 4 + 2) * 68 + fr] = gv.z;
    gT[(qc + e * 4 + 3) * 68 + fr] = gv.w;
  }
  __syncthreads();

  const int n4 = (t >> 4) * 4;     // 4 nodes
  const int k4 = (t & 15) * 4;     // 4 features
  float acc[4][4];
  #pragma unroll
  for (int i = 0; i < 4; i++)
    #pragma unroll
    for (int j = 0; j < 4; j++) acc[i][j] = 0.f;

  for (int f = 0; f < FE; f++) {
    f32x4 g = *(const f32x4*)(&gT[f * 68 + n4]);
    f32x4 w = *(const f32x4*)(&Wl[f * 68 + k4]);
    #pragma unroll
    for (int i = 0; i < 4; i++)
      #pragma unroll
      for (int j = 0; j < 4; j++)
        acc[i][j] = fmaf(g[i], w[j], acc[i][j]);
  }

  // s,d partials over this thread's 4 features
  float4 As = *(const float4*)(a + h * 2 * FE + k4);
  float4 Ad = *(const float4*)(a + h * 2 * FE + FE + k4);
  float sp[4], dp[4];
  #pragma unroll
  for (int i = 0; i < 4; i++) {
    sp[i] = acc[i][0] * As.x + acc[i][1] * As.y + acc[i][2] * As.z + acc[i][3] * As.w;
    dp[i] = acc[i][0] * Ad.x + acc[i][1] * Ad.y + acc[i][2] * Ad.z + acc[i][3] * Ad.w;
  }
  #pragma unroll
  for (int off = 1; off < 16; off <<= 1) {
    #pragma unroll
    for (int i = 0; i < 4; i++) {
      sp[i] += __shfl_xor(sp[i], off);
      dp[i] += __shfl_xor(dp[i], off);
    }
  }
  if ((t & 15) == 0) {
    #pragma unroll
    for (int i = 0; i < 4; i++) {
      st[h * NN + n0 + n4 + i] = sp[i] * LOG2E;
      dt[h * NN + n0 + n4 + i] = dp[i] * LOG2E;
    }
  }

  // stage bf16 transpose in LDS
  #pragma unroll
  for (int i = 0; i < 4; i++)
    #pragma unroll
    for (int j = 0; j < 4; j++) {
      __bf16 b = (__bf16)acc[i][j];
      lt[(k4 + j) * 64 + (n4 + i)] = __builtin_bit_cast(unsigned short, b);
    }
  __syncthreads();

  // coalesced global write of ltgT[h][k][n0..n0+64]
  const int kk = t >> 2;
  const int nc = (t & 3) * 16;
  uint4 v0 = *(const uint4*)(&lt[kk * 64 + nc]);
  uint4 v1 = *(const uint4*)(&lt[kk * 64 + nc + 8]);
  ushort* dst = ltgT + (size_t)h * FE * NN + kk * NN + n0 + nc;
  *(uint4*)(dst) = v0;
  *(uint4*)(dst + 8) = v1;
}

// ------------------------------------------------------------------
// Kernel 2: flash-style softmax(lrelu(s_i+d_j)) @ ltg via bf16 MFMA.
// i-tile = 16 rows (ONE 16-row MFMA group/wave), 4 waves split j
// (1024-j chunk each); partials reduced in LDS.
// grid (NN/16, NH) = 2048 blocks x 4 waves = 8192 waves = 8/SIMD,
// exactly one full-residency round. LDS 17.7 KB -> not the cap.
// A-frag (16x16x32): row = lane&15, k = (lane>>4)*8 + e.
// C/D: col = lane&15, row = (lane>>4)*4 + reg.
// ------------------------------------------------------------------
__global__ __launch_bounds__(256, 8) void gat_k2(
    const ushort* __restrict__ ltgT, const float* __restrict__ st,
    const float* __restrict__ dt, float* __restrict__ out)
{
  const int h    = blockIdx.y;
  const int i0   = blockIdx.x * 16;
  const int w    = threadIdx.x >> 6;     // wave 0..3 -> j chunk
  const int lane = threadIdx.x & 63;
  const int col  = lane & 15;
  const int koff = (lane >> 4) * 8;

  __shared__ float lds_pacc[4][16 * 68]; // stride 68 (==4 mod 32): free 2-way
  __shared__ float lds_z[4][16];

  const float*  dh  = dt + h * NN;
  const ushort* lth = ltgT + (size_t)h * FE * NN;

  const float sr0 = st[h * NN + i0 + col];

  f32x4 acc0[4], accZ0;
  #pragma unroll
  for (int tt = 0; tt < 4; tt++) acc0[tt] = (f32x4){0.f, 0.f, 0.f, 0.f};
  accZ0 = (f32x4){0.f, 0.f, 0.f, 0.f};

  bf16x8 ones;
  #pragma unroll
  for (int e = 0; e < 8; e++) ones[e] = (__bf16)1.0f;

  const int jbeg = w * (NN / 4);
  for (int j0 = jbeg; j0 < jbeg + NN / 4; j0 += 64) {
    const float* dp = dh + j0 + koff;
    float4 dA = *(const float4*)(dp);
    float4 dB = *(const float4*)(dp + 4);
    float4 dC = *(const float4*)(dp + 32);
    float4 dD = *(const float4*)(dp + 36);
    float dv[16] = {dA.x, dA.y, dA.z, dA.w, dB.x, dB.y, dB.z, dB.w,
                    dC.x, dC.y, dC.z, dC.w, dD.x, dD.y, dD.z, dD.w};

    bf16x8 af0[2];
    #pragma unroll
    for (int ks = 0; ks < 2; ks++) {
      #pragma unroll
      for (int e = 0; e < 8; e++) {
        const float x0 = sr0 + dv[ks * 8 + e];
        af0[ks][e] = (__bf16)EXP2F(fmaxf(x0, 0.2f * x0));  // 2^(lrelu(x~))
      }
    }

    #pragma unroll
    for (int tt = 0; tt < 4; tt++) {
      #pragma unroll
      for (int ks = 0; ks < 2; ks++) {
        bf16x8 bf = *(const bf16x8*)(const void*)(lth + (size_t)(tt * 16 + col) * NN + j0 + ks * 32 + koff);
        acc0[tt] = __builtin_amdgcn_mfma_f32_16x16x32_bf16(af0[ks], bf, acc0[tt], 0, 0, 0);
      }
    }
    #pragma unroll
    for (int ks = 0; ks < 2; ks++)
      accZ0 = __builtin_amdgcn_mfma_f32_16x16x32_bf16(af0[ks], ones, accZ0, 0, 0, 0);
  }

  // wave-partial Z per row: every col holds the same row-sum; col 0 writes
  const int rquad = (lane >> 4) * 4;
  if (col == 0) {
    #pragma unroll
    for (int reg = 0; reg < 4; reg++) lds_z[w][rquad + reg] = accZ0[reg];
  }

  // wave-partial accumulators to LDS
  #pragma unroll
  for (int tt = 0; tt < 4; tt++) {
    #pragma unroll
    for (int reg = 0; reg < 4; reg++)
      lds_pacc[w][(rquad + reg) * 68 + tt * 16 + col] = acc0[tt][reg];
  }
  __syncthreads();

  // cross-wave reduce: thread t -> row r = t>>4 (0..15), features f4 = (t&15)*4
  const int r  = threadIdx.x >> 4;
  const int f4 = (threadIdx.x & 15) * 4;
  f32x4 s = (f32x4){0.f, 0.f, 0.f, 0.f};
  float zz = 0.f;
  #pragma unroll
  for (int ww = 0; ww < 4; ww++) {
    s += *(const f32x4*)(&lds_pacc[ww][r * 68 + f4]);
    zz += lds_z[ww][r];
  }
  const float inv = 1.f / zz;
  f32x4 o = {s[0] * inv, s[1] * inv, s[2] * inv, s[3] * inv};
  *(f32x4*)(&out[((size_t)h * NN + i0 + r) * FE + f4]) = o;
}

extern "C" void kernel_launch(void* const* d_in, const int* in_sizes, int n_in,
                              void* d_out, int out_size, void* d_ws, size_t ws_size,
                              hipStream_t stream) {
  const float* graph = (const float*)d_in[0];
  const float* W     = (const float*)d_in[1];
  const float* a     = (const float*)d_in[2];
  float* outp        = (float*)d_out;

  // workspace layout (4.25 MiB total)
  char* p = (char*)d_ws;
  ushort* ltgT = (ushort*)p;              p += (size_t)NH * FE * NN * 2;   // 4 MiB
  float*  st   = (float*)p;               p += (size_t)NH * NN * 4;        // 128 KiB
  float*  dtp  = (float*)p;               p += (size_t)NH * NN * 4;        // 128 KiB

  dim3 g1(NN / 64, NH);
  gat_k1<<<g1, 256, 0, stream>>>(graph, W, a, ltgT, st, dtp);
  dim3 g2(NN / 16, NH);
  gat_k2<<<g2, 256, 0, stream>>>(ltgT, st, dtp, outp);
}

// Round 11
// 106.308 us; speedup vs baseline: 1.8578x; 1.8578x over previous
//
#include <hip/hip_runtime.h>
#include <hip/hip_bf16.h>

typedef __bf16 bf16x8 __attribute__((ext_vector_type(8)));
typedef float f32x4 __attribute__((ext_vector_type(4)));

static constexpr int NN = 4096;   // nodes
static constexpr int FE = 64;     // features
static constexpr int NH = 8;      // heads
#define LOG2E 1.44269504088896340736f

#if __has_builtin(__builtin_amdgcn_exp2f)
#define EXP2F(x) __builtin_amdgcn_exp2f(x)
#else
#define EXP2F(x) exp2f(x)
#endif

// ------------------------------------------------------------------
// Kernel 1: ltg = graph @ W[h]  (fp32), store ltgT (feature-major bf16),
//           s~ = (ltg . a_src)*log2e, d~ = (ltg . a_dst)*log2e
// grid (NN/64, NH), 256 threads   [unchanged]
// ------------------------------------------------------------------
__global__ __launch_bounds__(256) void gat_k1(
    const float* __restrict__ graph, const float* __restrict__ W,
    const float* __restrict__ a, ushort* __restrict__ ltgT,
    float* __restrict__ st, float* __restrict__ dt)
{
  const int h  = blockIdx.y;
  const int n0 = blockIdx.x * 64;
  const int t  = threadIdx.x;

  __shared__ float  Wl[64 * 68];   // Wl[f][k], padded
  __shared__ float  gT[64 * 68];   // gT[f][n], padded (graph transposed)
  __shared__ ushort lt[64 * 64];   // lt[k][n] bf16 staging for coalesced out

  const float* Wh = W + h * FE * FE;
  const int fr = t >> 2;           // row 0..63
  const int qc = (t & 3) * 16;     // col chunk
  #pragma unroll
  for (int e = 0; e < 4; e++) {
    float4 wv = *(const float4*)(Wh + fr * FE + qc + e * 4);
    *(float4*)(&Wl[fr * 68 + qc + e * 4]) = wv;
    float4 gv = *(const float4*)(graph + (n0 + fr) * FE + qc + e * 4);
    gT[(qc + e * 4 + 0) * 68 + fr] = gv.x;
    gT[(qc + e * 4 + 1) * 68 + fr] = gv.y;
    gT[(qc + e * 4 + 2) * 68 + fr] = gv.z;
    gT[(qc + e * 4 + 3) * 68 + fr] = gv.w;
  }
  __syncthreads();

  const int n4 = (t >> 4) * 4;     // 4 nodes
  const int k4 = (t & 15) * 4;     // 4 features
  float acc[4][4];
  #pragma unroll
  for (int i = 0; i < 4; i++)
    #pragma unroll
    for (int j = 0; j < 4; j++) acc[i][j] = 0.f;

  for (int f = 0; f < FE; f++) {
    f32x4 g = *(const f32x4*)(&gT[f * 68 + n4]);
    f32x4 w = *(const f32x4*)(&Wl[f * 68 + k4]);
    #pragma unroll
    for (int i = 0; i < 4; i++)
      #pragma unroll
      for (int j = 0; j < 4; j++)
        acc[i][j] = fmaf(g[i], w[j], acc[i][j]);
  }

  // s,d partials over this thread's 4 features
  float4 As = *(const float4*)(a + h * 2 * FE + k4);
  float4 Ad = *(const float4*)(a + h * 2 * FE + FE + k4);
  float sp[4], dp[4];
  #pragma unroll
  for (int i = 0; i < 4; i++) {
    sp[i] = acc[i][0] * As.x + acc[i][1] * As.y + acc[i][2] * As.z + acc[i][3] * As.w;
    dp[i] = acc[i][0] * Ad.x + acc[i][1] * Ad.y + acc[i][2] * Ad.z + acc[i][3] * Ad.w;
  }
  #pragma unroll
  for (int off = 1; off < 16; off <<= 1) {
    #pragma unroll
    for (int i = 0; i < 4; i++) {
      sp[i] += __shfl_xor(sp[i], off);
      dp[i] += __shfl_xor(dp[i], off);
    }
  }
  if ((t & 15) == 0) {
    #pragma unroll
    for (int i = 0; i < 4; i++) {
      st[h * NN + n0 + n4 + i] = sp[i] * LOG2E;
      dt[h * NN + n0 + n4 + i] = dp[i] * LOG2E;
    }
  }

  // stage bf16 transpose in LDS
  #pragma unroll
  for (int i = 0; i < 4; i++)
    #pragma unroll
    for (int j = 0; j < 4; j++) {
      __bf16 b = (__bf16)acc[i][j];
      lt[(k4 + j) * 64 + (n4 + i)] = __builtin_bit_cast(unsigned short, b);
    }
  __syncthreads();

  // coalesced global write of ltgT[h][k][n0..n0+64]
  const int kk = t >> 2;
  const int nc = (t & 3) * 16;
  uint4 v0 = *(const uint4*)(&lt[kk * 64 + nc]);
  uint4 v1 = *(const uint4*)(&lt[kk * 64 + nc + 8]);
  ushort* dst = ltgT + (size_t)h * FE * NN + kk * NN + n0 + nc;
  *(uint4*)(dst) = v0;
  *(uint4*)(dst + 8) = v1;
}

// ------------------------------------------------------------------
// Kernel 2: flash-style softmax(lrelu(s_i+d_j)) @ ltg via bf16 MFMA.
// R=64 rows per wave (FOUR 16-row MFMA groups) -> each B-fragment load
// is reused 4x (B-frags don't depend on i). 4 waves split j (1024 each),
// partials reduced in LDS. VMEM-gather instruction count = 1/2 of r8.
// grid (NN/64, NH) = 512 blocks x 4 waves; LDS 70.7 KB -> 2 blocks/CU.
// A-frag (16x16x32): row = lane&15, k = (lane>>4)*8 + e.
// C/D: col = lane&15, row = (lane>>4)*4 + reg.
// ------------------------------------------------------------------
__global__ __launch_bounds__(256, 2) void gat_k2(
    const ushort* __restrict__ ltgT, const float* __restrict__ st,
    const float* __restrict__ dt, float* __restrict__ out)
{
  const int h    = blockIdx.y;
  const int i0   = blockIdx.x * 64;
  const int w    = threadIdx.x >> 6;     // wave 0..3 -> j chunk
  const int lane = threadIdx.x & 63;
  const int col  = lane & 15;
  const int koff = (lane >> 4) * 8;

  __shared__ float lds_pacc[4][64 * 68]; // 69.6 KB; stride 68: free 2-way
  __shared__ float lds_z[4][64];

  const float*  dh  = dt + h * NN;
  const ushort* lth = ltgT + (size_t)h * FE * NN;

  float sr[4];
  #pragma unroll
  for (int g = 0; g < 4; g++) sr[g] = st[h * NN + i0 + g * 16 + col];

  f32x4 acc[4][4], accZ[4];
  #pragma unroll
  for (int g = 0; g < 4; g++) {
    #pragma unroll
    for (int tt = 0; tt < 4; tt++) acc[g][tt] = (f32x4){0.f, 0.f, 0.f, 0.f};
    accZ[g] = (f32x4){0.f, 0.f, 0.f, 0.f};
  }

  bf16x8 ones;
  #pragma unroll
  for (int e = 0; e < 8; e++) ones[e] = (__bf16)1.0f;

  const int jbeg = w * (NN / 4);
  for (int j0 = jbeg; j0 < jbeg + NN / 4; j0 += 64) {
    // dv loads (shared by all 4 row-groups)
    const float* dp = dh + j0 + koff;
    float4 dA = *(const float4*)(dp);
    float4 dB = *(const float4*)(dp + 4);
    float4 dC = *(const float4*)(dp + 32);
    float4 dD = *(const float4*)(dp + 36);
    float dv[16] = {dA.x, dA.y, dA.z, dA.w, dB.x, dB.y, dB.z, dB.w,
                    dC.x, dC.y, dC.z, dC.w, dD.x, dD.y, dD.z, dD.w};

    // B-fragments loaded ONCE per tile, reused by 4 row-groups (32 VGPR)
    bf16x8 bfr[4][2];
    #pragma unroll
    for (int tt = 0; tt < 4; tt++)
      #pragma unroll
      for (int ks = 0; ks < 2; ks++)
        bfr[tt][ks] = *(const bf16x8*)(const void*)(lth + (size_t)(tt * 16 + col) * NN + j0 + ks * 32 + koff);

    #pragma unroll
    for (int g = 0; g < 4; g++) {
      bf16x8 af[2];
      #pragma unroll
      for (int ks = 0; ks < 2; ks++) {
        #pragma unroll
        for (int e = 0; e < 8; e++) {
          const float x = sr[g] + dv[ks * 8 + e];
          af[ks][e] = (__bf16)EXP2F(fmaxf(x, 0.2f * x));  // 2^(lrelu(x~))
        }
      }
      #pragma unroll
      for (int tt = 0; tt < 4; tt++) {
        #pragma unroll
        for (int ks = 0; ks < 2; ks++)
          acc[g][tt] = __builtin_amdgcn_mfma_f32_16x16x32_bf16(af[ks], bfr[tt][ks], acc[g][tt], 0, 0, 0);
      }
      #pragma unroll
      for (int ks = 0; ks < 2; ks++)
        accZ[g] = __builtin_amdgcn_mfma_f32_16x16x32_bf16(af[ks], ones, accZ[g], 0, 0, 0);
    }
  }

  // wave-partial Z + accumulators to LDS
  const int rquad = (lane >> 4) * 4;
  #pragma unroll
  for (int g = 0; g < 4; g++) {
    if (col == 0) {
      #pragma unroll
      for (int reg = 0; reg < 4; reg++) lds_z[w][g * 16 + rquad + reg] = accZ[g][reg];
    }
    #pragma unroll
    for (int tt = 0; tt < 4; tt++) {
      #pragma unroll
      for (int reg = 0; reg < 4; reg++)
        lds_pacc[w][(g * 16 + rquad + reg) * 68 + tt * 16 + col] = acc[g][tt][reg];
    }
  }
  __syncthreads();

  // cross-wave reduce: thread t -> row r = t>>2 (0..63), 16 feats = (t&3)*16
  const int r   = threadIdx.x >> 2;
  const int f16 = (threadIdx.x & 3) * 16;
  f32x4 s0 = (f32x4){0.f,0.f,0.f,0.f}, s1 = s0, s2 = s0, s3 = s0;
  float zz = 0.f;
  #pragma unroll
  for (int ww = 0; ww < 4; ww++) {
    const float* pp = &lds_pacc[ww][r * 68 + f16];
    s0 += *(const f32x4*)(pp);
    s1 += *(const f32x4*)(pp + 4);
    s2 += *(const f32x4*)(pp + 8);
    s3 += *(const f32x4*)(pp + 12);
    zz += lds_z[ww][r];
  }
  const float inv = 1.f / zz;
  float* orow = &out[((size_t)h * NN + i0 + r) * FE + f16];
  f32x4 o0 = {s0[0]*inv, s0[1]*inv, s0[2]*inv, s0[3]*inv};
  f32x4 o1 = {s1[0]*inv, s1[1]*inv, s1[2]*inv, s1[3]*inv};
  f32x4 o2 = {s2[0]*inv, s2[1]*inv, s2[2]*inv, s2[3]*inv};
  f32x4 o3 = {s3[0]*inv, s3[1]*inv, s3[2]*inv, s3[3]*inv};
  *(f32x4*)(orow)      = o0;
  *(f32x4*)(orow + 4)  = o1;
  *(f32x4*)(orow + 8)  = o2;
  *(f32x4*)(orow + 12) = o3;
}

extern "C" void kernel_launch(void* const* d_in, const int* in_sizes, int n_in,
                              void* d_out, int out_size, void* d_ws, size_t ws_size,
                              hipStream_t stream) {
  const float* graph = (const float*)d_in[0];
  const float* W     = (const float*)d_in[1];
  const float* a     = (const float*)d_in[2];
  float* outp        = (float*)d_out;

  // workspace layout (4.25 MiB total)
  char* p = (char*)d_ws;
  ushort* ltgT = (ushort*)p;              p += (size_t)NH * FE * NN * 2;   // 4 MiB
  float*  st   = (float*)p;               p += (size_t)NH * NN * 4;        // 128 KiB
  float*  dtp  = (float*)p;               p += (size_t)NH * NN * 4;        // 128 KiB

  dim3 g1(NN / 64, NH);
  gat_k1<<<g1, 256, 0, stream>>>(graph, W, a, ltgT, st, dtp);
  dim3 g2(NN / 64, NH);
  gat_k2<<<g2, 256, 0, stream>>>(ltgT, st, dtp, outp);
}

// Round 13
// 106.026 us; speedup vs baseline: 1.8627x; 1.0027x over previous
//
#include <hip/hip_runtime.h>
#include <hip/hip_bf16.h>

typedef __bf16 bf16x8 __attribute__((ext_vector_type(8)));
typedef float f32x4 __attribute__((ext_vector_type(4)));

static constexpr int NN = 4096;   // nodes
static constexpr int FE = 64;     // features
static constexpr int NH = 8;      // heads
#define LOG2E 1.44269504088896340736f

#if __has_builtin(__builtin_amdgcn_exp2f)
#define EXP2F(x) __builtin_amdgcn_exp2f(x)
#else
#define EXP2F(x) exp2f(x)
#endif

static __device__ __forceinline__ ushort bf16_bits(float x) {
  __bf16 b = (__bf16)x;
  return __builtin_bit_cast(unsigned short, b);
}

// ------------------------------------------------------------------
// Kernel 1 (MFMA rewrite): ltg = graph @ W[h] via bf16 MFMA -> ltgT bf16.
// s~,d~ via exact factorization: wa = W·a_src (fp32), s = graph·wa (fp32)
// -> exponent path stays fp32 (reassociation only).
// grid (NN/64, NH), 256 threads (4 waves; wave w owns 16 node-rows).
// A-frag: graph rows direct from global (fp32->bf16).
// B-frag: W staged to LDS bf16 transposed Wt[k][f], stride 72 (2-way, free).
// ------------------------------------------------------------------
__global__ __launch_bounds__(256) void gat_k1(
    const float* __restrict__ graph, const float* __restrict__ W,
    const float* __restrict__ a, ushort* __restrict__ ltgT,
    float* __restrict__ st, float* __restrict__ dt)
{
  const int h    = blockIdx.y;
  const int n0   = blockIdx.x * 64;
  const int t    = threadIdx.x;
  const int w    = t >> 6;
  const int lane = t & 63;
  const int col  = lane & 15;
  const int koff = (lane >> 4) * 8;

  __shared__ ushort WtL[64 * 72];  // Wt[k][f] bf16, stride 72 (144 B, 16B-aligned)
  __shared__ ushort lt[64 * 72];   // lt[k][n] bf16 staging, stride 72
  __shared__ float  waL[2][64];    // wa_src / wa_dst (fp32)

  const float* Wh = W + h * FE * FE;

  // stage W -> WtL (bf16, transposed): thread t: f = t>>2, k-chunk = (t&3)*16
  {
    const int f  = t >> 2;
    const int kc = (t & 3) * 16;
    #pragma unroll
    for (int e = 0; e < 4; e++) {
      float4 wv = *(const float4*)(Wh + f * FE + kc + e * 4);
      WtL[(kc + e * 4 + 0) * 72 + f] = bf16_bits(wv.x);
      WtL[(kc + e * 4 + 1) * 72 + f] = bf16_bits(wv.y);
      WtL[(kc + e * 4 + 2) * 72 + f] = bf16_bits(wv.z);
      WtL[(kc + e * 4 + 3) * 72 + f] = bf16_bits(wv.w);
    }
  }

  // wa[sd][f] = sum_k W[f][k] * a_sd[k]   (fp32; waves 0,1)
  if (t < 128) {
    const int sd = t >> 6;
    const int f  = t & 63;
    const float* av = a + h * 2 * FE + sd * FE;
    const float* wr = Wh + f * FE;
    float s = 0.f;
    #pragma unroll
    for (int k = 0; k < FE; k += 4) {
      float4 wv = *(const float4*)(wr + k);
      float4 av4 = *(const float4*)(av + k);
      s += wv.x * av4.x + wv.y * av4.y + wv.z * av4.z + wv.w * av4.w;
    }
    waL[sd][f] = s;
  }
  __syncthreads();

  // MFMA: wave w computes node rows n0+w*16 .. +16, all 64 k.
  f32x4 acc[4];
  #pragma unroll
  for (int tt = 0; tt < 4; tt++) acc[tt] = (f32x4){0.f, 0.f, 0.f, 0.f};

  bf16x8 afr[2];
  const float* grow = graph + (size_t)(n0 + w * 16 + col) * FE;
  #pragma unroll
  for (int ks = 0; ks < 2; ks++) {
    float4 a0 = *(const float4*)(grow + ks * 32 + koff);
    float4 a1 = *(const float4*)(grow + ks * 32 + koff + 4);
    afr[ks][0] = (__bf16)a0.x; afr[ks][1] = (__bf16)a0.y;
    afr[ks][2] = (__bf16)a0.z; afr[ks][3] = (__bf16)a0.w;
    afr[ks][4] = (__bf16)a1.x; afr[ks][5] = (__bf16)a1.y;
    afr[ks][6] = (__bf16)a1.z; afr[ks][7] = (__bf16)a1.w;
  }
  #pragma unroll
  for (int tt = 0; tt < 4; tt++) {
    #pragma unroll
    for (int ks = 0; ks < 2; ks++) {
      bf16x8 bf = *(const bf16x8*)(const void*)(&WtL[(tt * 16 + col) * 72 + ks * 32 + koff]);
      acc[tt] = __builtin_amdgcn_mfma_f32_16x16x32_bf16(afr[ks], bf, acc[tt], 0, 0, 0);
    }
  }

  // s,d: fp32 dots graph[n] . wa[sd]   (waves 0,1; wave=sd, n = t&63)
  if (t < 128) {
    const int sd = t >> 6;
    const int n  = t & 63;
    const float* gr = graph + (size_t)(n0 + n) * FE;
    float s = 0.f;
    #pragma unroll
    for (int k = 0; k < FE; k += 4) {
      float4 g4 = *(const float4*)(gr + k);
      s += g4.x * waL[sd][k] + g4.y * waL[sd][k + 1] +
           g4.z * waL[sd][k + 2] + g4.w * waL[sd][k + 3];
    }
    float* outp = sd ? dt : st;
    outp[h * NN + n0 + n] = s * LOG2E;
  }

  // acc -> lt[k][n] (bf16)
  const int rquad = (lane >> 4) * 4;
  #pragma unroll
  for (int tt = 0; tt < 4; tt++) {
    #pragma unroll
    for (int reg = 0; reg < 4; reg++)
      lt[(tt * 16 + col) * 72 + w * 16 + rquad + reg] = bf16_bits(acc[tt][reg]);
  }
  __syncthreads();

  // coalesced global write of ltgT[h][k][n0..n0+64]
  const int kk = t >> 2;
  const int nc = (t & 3) * 16;
  uint4 v0 = *(const uint4*)(&lt[kk * 72 + nc]);
  uint4 v1 = *(const uint4*)(&lt[kk * 72 + nc + 8]);
  ushort* dst = ltgT + (size_t)h * FE * NN + kk * NN + n0 + nc;
  *(uint4*)(dst) = v0;
  *(uint4*)(dst + 8) = v1;
}

// ------------------------------------------------------------------
// Kernel 2 [UNCHANGED from round 9/11 measurement]:
// R=64 rows per wave (4 x 16-row MFMA groups), 4 waves split j,
// partials reduced in LDS. grid (NN/64, NH), 256 threads.
// ------------------------------------------------------------------
__global__ __launch_bounds__(256, 2) void gat_k2(
    const ushort* __restrict__ ltgT, const float* __restrict__ st,
    const float* __restrict__ dt, float* __restrict__ out)
{
  const int h    = blockIdx.y;
  const int i0   = blockIdx.x * 64;
  const int w    = threadIdx.x >> 6;     // wave 0..3 -> j chunk
  const int lane = threadIdx.x & 63;
  const int col  = lane & 15;
  const int koff = (lane >> 4) * 8;

  __shared__ float lds_pacc[4][64 * 68]; // 69.6 KB; stride 68: free 2-way
  __shared__ float lds_z[4][64];

  const float*  dh  = dt + h * NN;
  const ushort* lth = ltgT + (size_t)h * FE * NN;

  float sr[4];
  #pragma unroll
  for (int g = 0; g < 4; g++) sr[g] = st[h * NN + i0 + g * 16 + col];

  f32x4 acc[4][4], accZ[4];
  #pragma unroll
  for (int g = 0; g < 4; g++) {
    #pragma unroll
    for (int tt = 0; tt < 4; tt++) acc[g][tt] = (f32x4){0.f, 0.f, 0.f, 0.f};
    accZ[g] = (f32x4){0.f, 0.f, 0.f, 0.f};
  }

  bf16x8 ones;
  #pragma unroll
  for (int e = 0; e < 8; e++) ones[e] = (__bf16)1.0f;

  const int jbeg = w * (NN / 4);
  for (int j0 = jbeg; j0 < jbeg + NN / 4; j0 += 64) {
    // dv loads (shared by all 4 row-groups)
    const float* dp = dh + j0 + koff;
    float4 dA = *(const float4*)(dp);
    float4 dB = *(const float4*)(dp + 4);
    float4 dC = *(const float4*)(dp + 32);
    float4 dD = *(const float4*)(dp + 36);
    float dv[16] = {dA.x, dA.y, dA.z, dA.w, dB.x, dB.y, dB.z, dB.w,
                    dC.x, dC.y, dC.z, dC.w, dD.x, dD.y, dD.z, dD.w};

    // B-fragments loaded ONCE per tile, reused by 4 row-groups (32 VGPR)
    bf16x8 bfr[4][2];
    #pragma unroll
    for (int tt = 0; tt < 4; tt++)
      #pragma unroll
      for (int ks = 0; ks < 2; ks++)
        bfr[tt][ks] = *(const bf16x8*)(const void*)(lth + (size_t)(tt * 16 + col) * NN + j0 + ks * 32 + koff);

    #pragma unroll
    for (int g = 0; g < 4; g++) {
      bf16x8 af[2];
      #pragma unroll
      for (int ks = 0; ks < 2; ks++) {
        #pragma unroll
        for (int e = 0; e < 8; e++) {
          const float x = sr[g] + dv[ks * 8 + e];
          af[ks][e] = (__bf16)EXP2F(fmaxf(x, 0.2f * x));  // 2^(lrelu(x~))
        }
      }
      #pragma unroll
      for (int tt = 0; tt < 4; tt++) {
        #pragma unroll
        for (int ks = 0; ks < 2; ks++)
          acc[g][tt] = __builtin_amdgcn_mfma_f32_16x16x32_bf16(af[ks], bfr[tt][ks], acc[g][tt], 0, 0, 0);
      }
      #pragma unroll
      for (int ks = 0; ks < 2; ks++)
        accZ[g] = __builtin_amdgcn_mfma_f32_16x16x32_bf16(af[ks], ones, accZ[g], 0, 0, 0);
    }
  }

  // wave-partial Z + accumulators to LDS
  const int rquad = (lane >> 4) * 4;
  #pragma unroll
  for (int g = 0; g < 4; g++) {
    if (col == 0) {
      #pragma unroll
      for (int reg = 0; reg < 4; reg++) lds_z[w][g * 16 + rquad + reg] = accZ[g][reg];
    }
    #pragma unroll
    for (int tt = 0; tt < 4; tt++) {
      #pragma unroll
      for (int reg = 0; reg < 4; reg++)
        lds_pacc[w][(g * 16 + rquad + reg) * 68 + tt * 16 + col] = acc[g][tt][reg];
    }
  }
  __syncthreads();

  // cross-wave reduce: thread t -> row r = t>>2 (0..63), 16 feats = (t&3)*16
  const int r   = threadIdx.x >> 2;
  const int f16 = (threadIdx.x & 3) * 16;
  f32x4 s0 = (f32x4){0.f,0.f,0.f,0.f}, s1 = s0, s2 = s0, s3 = s0;
  float zz = 0.f;
  #pragma unroll
  for (int ww = 0; ww < 4; ww++) {
    const float* pp = &lds_pacc[ww][r * 68 + f16];
    s0 += *(const f32x4*)(pp);
    s1 += *(const f32x4*)(pp + 4);
    s2 += *(const f32x4*)(pp + 8);
    s3 += *(const f32x4*)(pp + 12);
    zz += lds_z[ww][r];
  }
  const float inv = 1.f / zz;
  float* orow = &out[((size_t)h * NN + i0 + r) * FE + f16];
  f32x4 o0 = {s0[0]*inv, s0[1]*inv, s0[2]*inv, s0[3]*inv};
  f32x4 o1 = {s1[0]*inv, s1[1]*inv, s1[2]*inv, s1[3]*inv};
  f32x4 o2 = {s2[0]*inv, s2[1]*inv, s2[2]*inv, s2[3]*inv};
  f32x4 o3 = {s3[0]*inv, s3[1]*inv, s3[2]*inv, s3[3]*inv};
  *(f32x4*)(orow)      = o0;
  *(f32x4*)(orow + 4)  = o1;
  *(f32x4*)(orow + 8)  = o2;
  *(f32x4*)(orow + 12) = o3;
}

extern "C" void kernel_launch(void* const* d_in, const int* in_sizes, int n_in,
                              void* d_out, int out_size, void* d_ws, size_t ws_size,
                              hipStream_t stream) {
  const float* graph = (const float*)d_in[0];
  const float* W     = (const float*)d_in[1];
  const float* a     = (const float*)d_in[2];
  float* outp        = (float*)d_out;

  // workspace layout (4.25 MiB total)
  char* p = (char*)d_ws;
  ushort* ltgT = (ushort*)p;              p += (size_t)NH * FE * NN * 2;   // 4 MiB
  float*  st   = (float*)p;               p += (size_t)NH * NN * 4;        // 128 KiB
  float*  dtp  = (float*)p;               p += (size_t)NH * NN * 4;        // 128 KiB

  dim3 g1(NN / 64, NH);
  gat_k1<<<g1, 256, 0, stream>>>(graph, W, a, ltgT, st, dtp);
  dim3 g2(NN / 64, NH);
  gat_k2<<<g2, 256, 0, stream>>>(ltgT, st, dtp, outp);
}

// Round 14
// 101.183 us; speedup vs baseline: 1.9519x; 1.0479x over previous
//
#include <hip/hip_runtime.h>
#include <hip/hip_bf16.h>

typedef __bf16 bf16x8 __attribute__((ext_vector_type(8)));
typedef float f32x4 __attribute__((ext_vector_type(4)));

static constexpr int NN = 4096;   // nodes
static constexpr int FE = 64;     // features
static constexpr int NH = 8;      // heads
#define LOG2E 1.44269504088896340736f

#if __has_builtin(__builtin_amdgcn_exp2f)
#define EXP2F(x) __builtin_amdgcn_exp2f(x)
#else
#define EXP2F(x) exp2f(x)
#endif

static __device__ __forceinline__ ushort bf16_bits(float x) {
  __bf16 b = (__bf16)x;
  return __builtin_bit_cast(unsigned short, b);
}

// ------------------------------------------------------------------
// Kernel 1: ltg = graph @ W[h] via bf16 MFMA; OUTPUT IN FRAGMENT-TILED
// ORDER ltgB: per (head, j-tile of 64, tt, ks) a 1KB block = lane l's
// bf16x8 at offset l*16B  (exactly k2's register consumption order).
// s~,d~ via exact fp32 factorization (unchanged from r11).
// grid (NN/64, NH), 256 threads.
// ------------------------------------------------------------------
__global__ __launch_bounds__(256) void gat_k1(
    const float* __restrict__ graph, const float* __restrict__ W,
    const float* __restrict__ a, ushort* __restrict__ ltgB,
    float* __restrict__ st, float* __restrict__ dt)
{
  const int h    = blockIdx.y;
  const int n0   = blockIdx.x * 64;
  const int t    = threadIdx.x;
  const int w    = t >> 6;
  const int lane = t & 63;
  const int col  = lane & 15;
  const int koff = (lane >> 4) * 8;

  __shared__ ushort WtL[64 * 72];  // Wt[k][f] bf16, stride 72
  __shared__ ushort lt[64 * 72];   // lt[f][n_local] bf16 staging, stride 72
  __shared__ float  waL[2][64];    // wa_src / wa_dst (fp32)

  const float* Wh = W + h * FE * FE;

  // stage W -> WtL (bf16, transposed): thread t: f = t>>2, k-chunk = (t&3)*16
  {
    const int f  = t >> 2;
    const int kc = (t & 3) * 16;
    #pragma unroll
    for (int e = 0; e < 4; e++) {
      float4 wv = *(const float4*)(Wh + f * FE + kc + e * 4);
      WtL[(kc + e * 4 + 0) * 72 + f] = bf16_bits(wv.x);
      WtL[(kc + e * 4 + 1) * 72 + f] = bf16_bits(wv.y);
      WtL[(kc + e * 4 + 2) * 72 + f] = bf16_bits(wv.z);
      WtL[(kc + e * 4 + 3) * 72 + f] = bf16_bits(wv.w);
    }
  }

  // wa[sd][f] = sum_k W[f][k] * a_sd[k]   (fp32; waves 0,1)
  if (t < 128) {
    const int sd = t >> 6;
    const int f  = t & 63;
    const float* av = a + h * 2 * FE + sd * FE;
    const float* wr = Wh + f * FE;
    float s = 0.f;
    #pragma unroll
    for (int k = 0; k < FE; k += 4) {
      float4 wv = *(const float4*)(wr + k);
      float4 av4 = *(const float4*)(av + k);
      s += wv.x * av4.x + wv.y * av4.y + wv.z * av4.z + wv.w * av4.w;
    }
    waL[sd][f] = s;
  }
  __syncthreads();

  // MFMA: wave w computes node rows n0+w*16 .. +16, all 64 features.
  f32x4 acc[4];
  #pragma unroll
  for (int tt = 0; tt < 4; tt++) acc[tt] = (f32x4){0.f, 0.f, 0.f, 0.f};

  bf16x8 afr[2];
  const float* grow = graph + (size_t)(n0 + w * 16 + col) * FE;
  #pragma unroll
  for (int ks = 0; ks < 2; ks++) {
    float4 a0 = *(const float4*)(grow + ks * 32 + koff);
    float4 a1 = *(const float4*)(grow + ks * 32 + koff + 4);
    afr[ks][0] = (__bf16)a0.x; afr[ks][1] = (__bf16)a0.y;
    afr[ks][2] = (__bf16)a0.z; afr[ks][3] = (__bf16)a0.w;
    afr[ks][4] = (__bf16)a1.x; afr[ks][5] = (__bf16)a1.y;
    afr[ks][6] = (__bf16)a1.z; afr[ks][7] = (__bf16)a1.w;
  }
  #pragma unroll
  for (int tt = 0; tt < 4; tt++) {
    #pragma unroll
    for (int ks = 0; ks < 2; ks++) {
      bf16x8 bf = *(const bf16x8*)(const void*)(&WtL[(tt * 16 + col) * 72 + ks * 32 + koff]);
      acc[tt] = __builtin_amdgcn_mfma_f32_16x16x32_bf16(afr[ks], bf, acc[tt], 0, 0, 0);
    }
  }

  // s,d: fp32 dots graph[n] . wa[sd]   (waves 0,1; wave=sd, n = t&63)
  if (t < 128) {
    const int sd = t >> 6;
    const int n  = t & 63;
    const float* gr = graph + (size_t)(n0 + n) * FE;
    float s = 0.f;
    #pragma unroll
    for (int k = 0; k < FE; k += 4) {
      float4 g4 = *(const float4*)(gr + k);
      s += g4.x * waL[sd][k] + g4.y * waL[sd][k + 1] +
           g4.z * waL[sd][k + 2] + g4.w * waL[sd][k + 3];
    }
    float* outp = sd ? dt : st;
    outp[h * NN + n0 + n] = s * LOG2E;
  }

  // acc -> lt[f][n_local] (bf16); D: col=lane&15 (feature), row=(lane>>4)*4+reg (node)
  const int rquad = (lane >> 4) * 4;
  #pragma unroll
  for (int tt = 0; tt < 4; tt++) {
    #pragma unroll
    for (int reg = 0; reg < 4; reg++)
      lt[(tt * 16 + col) * 72 + w * 16 + rquad + reg] = bf16_bits(acc[tt][reg]);
  }
  __syncthreads();

  // fragment-tiled global write: block (h, n0/64, ttks) of 512 ushorts;
  // lane l's 8 ushorts = lt[f = tt*16 + (l&15)][jl = ks*32 + (l>>4)*8 .. +8]
  {
    const int ttks = t >> 5;            // 0..7 = tt*2+ks
    const int tt_  = ttks >> 1, ks_ = ttks & 1;
    const int l0   = (t & 31) * 2;      // two lanes per thread
    ushort* dstB = ltgB + (((size_t)h * (NN / 64) + (n0 >> 6)) * 8 + ttks) * 512;
    #pragma unroll
    for (int q = 0; q < 2; q++) {
      const int l  = l0 + q;
      const int f  = tt_ * 16 + (l & 15);
      const int jl = ks_ * 32 + (l >> 4) * 8;
      uint4 v = *(const uint4*)(&lt[f * 72 + jl]);
      *(uint4*)(dstB + (size_t)l * 8) = v;
    }
  }
}

// ------------------------------------------------------------------
// Kernel 2: identical loop/compute to the measured 44 µs version;
// ONLY the B-fragment load addressing changed: fragment-tiled ltgB
// -> each load is lane*16B within a contiguous 1KB block (coalesced).
// R=64 rows/wave, 4 waves split j, LDS partial reduce.
// grid (NN/64, NH), 256 threads.
// ------------------------------------------------------------------
__global__ __launch_bounds__(256, 2) void gat_k2(
    const ushort* __restrict__ ltgB, const float* __restrict__ st,
    const float* __restrict__ dt, float* __restrict__ out)
{
  const int h    = blockIdx.y;
  const int i0   = blockIdx.x * 64;
  const int w    = threadIdx.x >> 6;     // wave 0..3 -> j chunk
  const int lane = threadIdx.x & 63;
  const int col  = lane & 15;
  const int koff = (lane >> 4) * 8;

  __shared__ float lds_pacc[4][64 * 68]; // 69.6 KB; stride 68: free 2-way
  __shared__ float lds_z[4][64];

  const float* dh = dt + h * NN;

  float sr[4];
  #pragma unroll
  for (int g = 0; g < 4; g++) sr[g] = st[h * NN + i0 + g * 16 + col];

  f32x4 acc[4][4], accZ[4];
  #pragma unroll
  for (int g = 0; g < 4; g++) {
    #pragma unroll
    for (int tt = 0; tt < 4; tt++) acc[g][tt] = (f32x4){0.f, 0.f, 0.f, 0.f};
    accZ[g] = (f32x4){0.f, 0.f, 0.f, 0.f};
  }

  bf16x8 ones;
  #pragma unroll
  for (int e = 0; e < 8; e++) ones[e] = (__bf16)1.0f;

  const int jbeg = w * (NN / 4);
  for (int j0 = jbeg; j0 < jbeg + NN / 4; j0 += 64) {
    // dv loads (shared by all 4 row-groups)
    const float* dp = dh + j0 + koff;
    float4 dA = *(const float4*)(dp);
    float4 dB = *(const float4*)(dp + 4);
    float4 dC = *(const float4*)(dp + 32);
    float4 dD = *(const float4*)(dp + 36);
    float dv[16] = {dA.x, dA.y, dA.z, dA.w, dB.x, dB.y, dB.z, dB.w,
                    dC.x, dC.y, dC.z, dC.w, dD.x, dD.y, dD.z, dD.w};

    // B-fragments: fragment-tiled -> fully coalesced 1KB blocks
    const ushort* bsrc = ltgB + (((size_t)h * (NN / 64) + (j0 >> 6)) * 8) * 512 + (size_t)lane * 8;
    bf16x8 bfr[4][2];
    #pragma unroll
    for (int tt = 0; tt < 4; tt++)
      #pragma unroll
      for (int ks = 0; ks < 2; ks++)
        bfr[tt][ks] = *(const bf16x8*)(const void*)(bsrc + (tt * 2 + ks) * 512);

    #pragma unroll
    for (int g = 0; g < 4; g++) {
      bf16x8 af[2];
      #pragma unroll
      for (int ks = 0; ks < 2; ks++) {
        #pragma unroll
        for (int e = 0; e < 8; e++) {
          const float x = sr[g] + dv[ks * 8 + e];
          af[ks][e] = (__bf16)EXP2F(fmaxf(x, 0.2f * x));  // 2^(lrelu(x~))
        }
      }
      #pragma unroll
      for (int tt = 0; tt < 4; tt++) {
        #pragma unroll
        for (int ks = 0; ks < 2; ks++)
          acc[g][tt] = __builtin_amdgcn_mfma_f32_16x16x32_bf16(af[ks], bfr[tt][ks], acc[g][tt], 0, 0, 0);
      }
      #pragma unroll
      for (int ks = 0; ks < 2; ks++)
        accZ[g] = __builtin_amdgcn_mfma_f32_16x16x32_bf16(af[ks], ones, accZ[g], 0, 0, 0);
    }
  }

  // wave-partial Z + accumulators to LDS
  const int rquad = (lane >> 4) * 4;
  #pragma unroll
  for (int g = 0; g < 4; g++) {
    if (col == 0) {
      #pragma unroll
      for (int reg = 0; reg < 4; reg++) lds_z[w][g * 16 + rquad + reg] = accZ[g][reg];
    }
    #pragma unroll
    for (int tt = 0; tt < 4; tt++) {
      #pragma unroll
      for (int reg = 0; reg < 4; reg++)
        lds_pacc[w][(g * 16 + rquad + reg) * 68 + tt * 16 + col] = acc[g][tt][reg];
    }
  }
  __syncthreads();

  // cross-wave reduce: thread t -> row r = t>>2 (0..63), 16 feats = (t&3)*16
  const int r   = threadIdx.x >> 2;
  const int f16 = (threadIdx.x & 3) * 16;
  f32x4 s0 = (f32x4){0.f,0.f,0.f,0.f}, s1 = s0, s2 = s0, s3 = s0;
  float zz = 0.f;
  #pragma unroll
  for (int ww = 0; ww < 4; ww++) {
    const float* pp = &lds_pacc[ww][r * 68 + f16];
    s0 += *(const f32x4*)(pp);
    s1 += *(const f32x4*)(pp + 4);
    s2 += *(const f32x4*)(pp + 8);
    s3 += *(const f32x4*)(pp + 12);
    zz += lds_z[ww][r];
  }
  const float inv = 1.f / zz;
  float* orow = &out[((size_t)h * NN + i0 + r) * FE + f16];
  f32x4 o0 = {s0[0]*inv, s0[1]*inv, s0[2]*inv, s0[3]*inv};
  f32x4 o1 = {s1[0]*inv, s1[1]*inv, s1[2]*inv, s1[3]*inv};
  f32x4 o2 = {s2[0]*inv, s2[1]*inv, s2[2]*inv, s2[3]*inv};
  f32x4 o3 = {s3[0]*inv, s3[1]*inv, s3[2]*inv, s3[3]*inv};
  *(f32x4*)(orow)      = o0;
  *(f32x4*)(orow + 4)  = o1;
  *(f32x4*)(orow + 8)  = o2;
  *(f32x4*)(orow + 12) = o3;
}

extern "C" void kernel_launch(void* const* d_in, const int* in_sizes, int n_in,
                              void* d_out, int out_size, void* d_ws, size_t ws_size,
                              hipStream_t stream) {
  const float* graph = (const float*)d_in[0];
  const float* W     = (const float*)d_in[1];
  const float* a     = (const float*)d_in[2];
  float* outp        = (float*)d_out;

  // workspace layout (4.25 MiB total)
  char* p = (char*)d_ws;
  ushort* ltgB = (ushort*)p;              p += (size_t)NH * FE * NN * 2;   // 4 MiB (tiled)
  float*  st   = (float*)p;               p += (size_t)NH * NN * 4;        // 128 KiB
  float*  dtp  = (float*)p;               p += (size_t)NH * NN * 4;        // 128 KiB

  dim3 g1(NN / 64, NH);
  gat_k1<<<g1, 256, 0, stream>>>(graph, W, a, ltgB, st, dtp);
  dim3 g2(NN / 64, NH);
  gat_k2<<<g2, 256, 0, stream>>>(ltgB, st, dtp, outp);
}

// Round 15
// 100.407 us; speedup vs baseline: 1.9670x; 1.0077x over previous
//
#include <hip/hip_runtime.h>
#include <hip/hip_bf16.h>

typedef __bf16 bf16x8 __attribute__((ext_vector_type(8)));
typedef float f32x4 __attribute__((ext_vector_type(4)));

static constexpr int NN = 4096;   // nodes
static constexpr int FE = 64;     // features
static constexpr int NH = 8;      // heads
#define LOG2E 1.44269504088896340736f

#if __has_builtin(__builtin_amdgcn_exp2f)
#define EXP2F(x) __builtin_amdgcn_exp2f(x)
#else
#define EXP2F(x) exp2f(x)
#endif

static __device__ __forceinline__ ushort bf16_bits(float x) {
  __bf16 b = (__bf16)x;
  return __builtin_bit_cast(unsigned short, b);
}

// ------------------------------------------------------------------
// Kernel 1 [UNCHANGED from round 14]: ltg = graph @ W[h] via bf16 MFMA;
// output fragment-tiled ltgB (1KB block per (h, j-tile, tt, ks)).
// s~,d~ via exact fp32 factorization.
// grid (NN/64, NH), 256 threads.
// ------------------------------------------------------------------
__global__ __launch_bounds__(256) void gat_k1(
    const float* __restrict__ graph, const float* __restrict__ W,
    const float* __restrict__ a, ushort* __restrict__ ltgB,
    float* __restrict__ st, float* __restrict__ dt)
{
  const int h    = blockIdx.y;
  const int n0   = blockIdx.x * 64;
  const int t    = threadIdx.x;
  const int w    = t >> 6;
  const int lane = t & 63;
  const int col  = lane & 15;
  const int koff = (lane >> 4) * 8;

  __shared__ ushort WtL[64 * 72];  // Wt[k][f] bf16, stride 72
  __shared__ ushort lt[64 * 72];   // lt[f][n_local] bf16 staging, stride 72
  __shared__ float  waL[2][64];    // wa_src / wa_dst (fp32)

  const float* Wh = W + h * FE * FE;

  // stage W -> WtL (bf16, transposed)
  {
    const int f  = t >> 2;
    const int kc = (t & 3) * 16;
    #pragma unroll
    for (int e = 0; e < 4; e++) {
      float4 wv = *(const float4*)(Wh + f * FE + kc + e * 4);
      WtL[(kc + e * 4 + 0) * 72 + f] = bf16_bits(wv.x);
      WtL[(kc + e * 4 + 1) * 72 + f] = bf16_bits(wv.y);
      WtL[(kc + e * 4 + 2) * 72 + f] = bf16_bits(wv.z);
      WtL[(kc + e * 4 + 3) * 72 + f] = bf16_bits(wv.w);
    }
  }

  // wa[sd][f] = sum_k W[f][k] * a_sd[k]   (fp32; waves 0,1)
  if (t < 128) {
    const int sd = t >> 6;
    const int f  = t & 63;
    const float* av = a + h * 2 * FE + sd * FE;
    const float* wr = Wh + f * FE;
    float s = 0.f;
    #pragma unroll
    for (int k = 0; k < FE; k += 4) {
      float4 wv = *(const float4*)(wr + k);
      float4 av4 = *(const float4*)(av + k);
      s += wv.x * av4.x + wv.y * av4.y + wv.z * av4.z + wv.w * av4.w;
    }
    waL[sd][f] = s;
  }
  __syncthreads();

  // MFMA: wave w computes node rows n0+w*16 .. +16, all 64 features.
  f32x4 acc[4];
  #pragma unroll
  for (int tt = 0; tt < 4; tt++) acc[tt] = (f32x4){0.f, 0.f, 0.f, 0.f};

  bf16x8 afr[2];
  const float* grow = graph + (size_t)(n0 + w * 16 + col) * FE;
  #pragma unroll
  for (int ks = 0; ks < 2; ks++) {
    float4 a0 = *(const float4*)(grow + ks * 32 + koff);
    float4 a1 = *(const float4*)(grow + ks * 32 + koff + 4);
    afr[ks][0] = (__bf16)a0.x; afr[ks][1] = (__bf16)a0.y;
    afr[ks][2] = (__bf16)a0.z; afr[ks][3] = (__bf16)a0.w;
    afr[ks][4] = (__bf16)a1.x; afr[ks][5] = (__bf16)a1.y;
    afr[ks][6] = (__bf16)a1.z; afr[ks][7] = (__bf16)a1.w;
  }
  #pragma unroll
  for (int tt = 0; tt < 4; tt++) {
    #pragma unroll
    for (int ks = 0; ks < 2; ks++) {
      bf16x8 bf = *(const bf16x8*)(const void*)(&WtL[(tt * 16 + col) * 72 + ks * 32 + koff]);
      acc[tt] = __builtin_amdgcn_mfma_f32_16x16x32_bf16(afr[ks], bf, acc[tt], 0, 0, 0);
    }
  }

  // s,d: fp32 dots graph[n] . wa[sd]   (waves 0,1)
  if (t < 128) {
    const int sd = t >> 6;
    const int n  = t & 63;
    const float* gr = graph + (size_t)(n0 + n) * FE;
    float s = 0.f;
    #pragma unroll
    for (int k = 0; k < FE; k += 4) {
      float4 g4 = *(const float4*)(gr + k);
      s += g4.x * waL[sd][k] + g4.y * waL[sd][k + 1] +
           g4.z * waL[sd][k + 2] + g4.w * waL[sd][k + 3];
    }
    float* outp = sd ? dt : st;
    outp[h * NN + n0 + n] = s * LOG2E;
  }

  // acc -> lt[f][n_local] (bf16)
  const int rquad = (lane >> 4) * 4;
  #pragma unroll
  for (int tt = 0; tt < 4; tt++) {
    #pragma unroll
    for (int reg = 0; reg < 4; reg++)
      lt[(tt * 16 + col) * 72 + w * 16 + rquad + reg] = bf16_bits(acc[tt][reg]);
  }
  __syncthreads();

  // fragment-tiled global write
  {
    const int ttks = t >> 5;            // 0..7 = tt*2+ks
    const int tt_  = ttks >> 1, ks_ = ttks & 1;
    const int l0   = (t & 31) * 2;      // two lanes per thread
    ushort* dstB = ltgB + (((size_t)h * (NN / 64) + (n0 >> 6)) * 8 + ttks) * 512;
    #pragma unroll
    for (int q = 0; q < 2; q++) {
      const int l  = l0 + q;
      const int f  = tt_ * 16 + (l & 15);
      const int jl = ks_ * 32 + (l >> 4) * 8;
      uint4 v = *(const uint4*)(&lt[f * 72 + jl]);
      *(uint4*)(dstB + (size_t)l * 8) = v;
    }
  }
}

// ------------------------------------------------------------------
// Kernel 2: same math/layout as the measured round-14 version; j-loop
// 2x UNROLLED with explicit A/B register double-buffers (B-frags + dv)
// so next-tile loads issue before current-tile compute (SW pipeline).
// R=64 rows/wave, 4 waves split j, LDS partial reduce.
// grid (NN/64, NH), 256 threads.
// ------------------------------------------------------------------
__global__ __launch_bounds__(256, 2) void gat_k2(
    const ushort* __restrict__ ltgB, const float* __restrict__ st,
    const float* __restrict__ dt, float* __restrict__ out)
{
  const int h    = blockIdx.y;
  const int i0   = blockIdx.x * 64;
  const int w    = threadIdx.x >> 6;     // wave 0..3 -> j chunk
  const int lane = threadIdx.x & 63;
  const int col  = lane & 15;
  const int koff = (lane >> 4) * 8;

  __shared__ float lds_pacc[4][64 * 68]; // 69.6 KB; stride 68: free 2-way
  __shared__ float lds_z[4][64];

  const float* dh = dt + h * NN;

  float sr[4];
  #pragma unroll
  for (int g = 0; g < 4; g++) sr[g] = st[h * NN + i0 + g * 16 + col];

  f32x4 acc[4][4], accZ[4];
  #pragma unroll
  for (int g = 0; g < 4; g++) {
    #pragma unroll
    for (int tt = 0; tt < 4; tt++) acc[g][tt] = (f32x4){0.f, 0.f, 0.f, 0.f};
    accZ[g] = (f32x4){0.f, 0.f, 0.f, 0.f};
  }

  bf16x8 ones;
  #pragma unroll
  for (int e = 0; e < 8; e++) ones[e] = (__bf16)1.0f;

  bf16x8 bfrA[4][2], bfrB[4][2];
  float dvA[16], dvB[16];

#define LOADTILE(BFR, DV, J0)                                                  \
  {                                                                            \
    const float* dp_ = dh + (J0) + koff;                                       \
    float4 d0_ = *(const float4*)(dp_);                                        \
    float4 d1_ = *(const float4*)(dp_ + 4);                                    \
    float4 d2_ = *(const float4*)(dp_ + 32);                                   \
    float4 d3_ = *(const float4*)(dp_ + 36);                                   \
    DV[0]=d0_.x; DV[1]=d0_.y; DV[2]=d0_.z; DV[3]=d0_.w;                        \
    DV[4]=d1_.x; DV[5]=d1_.y; DV[6]=d1_.z; DV[7]=d1_.w;                        \
    DV[8]=d2_.x; DV[9]=d2_.y; DV[10]=d2_.z; DV[11]=d2_.w;                      \
    DV[12]=d3_.x; DV[13]=d3_.y; DV[14]=d3_.z; DV[15]=d3_.w;                    \
    const ushort* bsrc_ = ltgB + (((size_t)h * (NN / 64) + ((J0) >> 6)) * 8) * 512 \
                          + (size_t)lane * 8;                                  \
    _Pragma("unroll")                                                          \
    for (int tt = 0; tt < 4; tt++)                                             \
      _Pragma("unroll")                                                        \
      for (int ks = 0; ks < 2; ks++)                                           \
        BFR[tt][ks] = *(const bf16x8*)(const void*)(bsrc_ + (tt * 2 + ks) * 512); \
  }

#define COMPUTETILE(BFR, DV)                                                   \
  _Pragma("unroll")                                                            \
  for (int g = 0; g < 4; g++) {                                                \
    bf16x8 af[2];                                                              \
    _Pragma("unroll")                                                          \
    for (int ks = 0; ks < 2; ks++) {                                           \
      _Pragma("unroll")                                                        \
      for (int e = 0; e < 8; e++) {                                            \
        const float x_ = sr[g] + DV[ks * 8 + e];                               \
        af[ks][e] = (__bf16)EXP2F(fmaxf(x_, 0.2f * x_));                       \
      }                                                                        \
    }                                                                          \
    _Pragma("unroll")                                                          \
    for (int tt = 0; tt < 4; tt++) {                                           \
      _Pragma("unroll")                                                        \
      for (int ks = 0; ks < 2; ks++)                                           \
        acc[g][tt] = __builtin_amdgcn_mfma_f32_16x16x32_bf16(af[ks], BFR[tt][ks], acc[g][tt], 0, 0, 0); \
    }                                                                          \
    _Pragma("unroll")                                                          \
    for (int ks = 0; ks < 2; ks++)                                             \
      accZ[g] = __builtin_amdgcn_mfma_f32_16x16x32_bf16(af[ks], ones, accZ[g], 0, 0, 0); \
  }

  const int jbeg = w * (NN / 4);
  const int jend = jbeg + NN / 4;          // 16 tiles -> 8 double-iterations
  LOADTILE(bfrA, dvA, jbeg);
  for (int j0 = jbeg; j0 < jend; j0 += 128) {
    LOADTILE(bfrB, dvB, j0 + 64);          // prefetch odd tile
    COMPUTETILE(bfrA, dvA);
    if (j0 + 128 < jend) LOADTILE(bfrA, dvA, j0 + 128);  // prefetch next even
    COMPUTETILE(bfrB, dvB);
  }
#undef LOADTILE
#undef COMPUTETILE

  // wave-partial Z + accumulators to LDS
  const int rquad = (lane >> 4) * 4;
  #pragma unroll
  for (int g = 0; g < 4; g++) {
    if (col == 0) {
      #pragma unroll
      for (int reg = 0; reg < 4; reg++) lds_z[w][g * 16 + rquad + reg] = accZ[g][reg];
    }
    #pragma unroll
    for (int tt = 0; tt < 4; tt++) {
      #pragma unroll
      for (int reg = 0; reg < 4; reg++)
        lds_pacc[w][(g * 16 + rquad + reg) * 68 + tt * 16 + col] = acc[g][tt][reg];
    }
  }
  __syncthreads();

  // cross-wave reduce: thread t -> row r = t>>2 (0..63), 16 feats = (t&3)*16
  const int r   = threadIdx.x >> 2;
  const int f16 = (threadIdx.x & 3) * 16;
  f32x4 s0 = (f32x4){0.f,0.f,0.f,0.f}, s1 = s0, s2 = s0, s3 = s0;
  float zz = 0.f;
  #pragma unroll
  for (int ww = 0; ww < 4; ww++) {
    const float* pp = &lds_pacc[ww][r * 68 + f16];
    s0 += *(const f32x4*)(pp);
    s1 += *(const f32x4*)(pp + 4);
    s2 += *(const f32x4*)(pp + 8);
    s3 += *(const f32x4*)(pp + 12);
    zz += lds_z[ww][r];
  }
  const float inv = 1.f / zz;
  float* orow = &out[((size_t)h * NN + i0 + r) * FE + f16];
  f32x4 o0 = {s0[0]*inv, s0[1]*inv, s0[2]*inv, s0[3]*inv};
  f32x4 o1 = {s1[0]*inv, s1[1]*inv, s1[2]*inv, s1[3]*inv};
  f32x4 o2 = {s2[0]*inv, s2[1]*inv, s2[2]*inv, s2[3]*inv};
  f32x4 o3 = {s3[0]*inv, s3[1]*inv, s3[2]*inv, s3[3]*inv};
  *(f32x4*)(orow)      = o0;
  *(f32x4*)(orow + 4)  = o1;
  *(f32x4*)(orow + 8)  = o2;
  *(f32x4*)(orow + 12) = o3;
}

extern "C" void kernel_launch(void* const* d_in, const int* in_sizes, int n_in,
                              void* d_out, int out_size, void* d_ws, size_t ws_size,
                              hipStream_t stream) {
  const float* graph = (const float*)d_in[0];
  const float* W     = (const float*)d_in[1];
  const float* a     = (const float*)d_in[2];
  float* outp        = (float*)d_out;

  // workspace layout (4.25 MiB total)
  char* p = (char*)d_ws;
  ushort* ltgB = (ushort*)p;              p += (size_t)NH * FE * NN * 2;   // 4 MiB (tiled)
  float*  st   = (float*)p;               p += (size_t)NH * NN * 4;        // 128 KiB
  float*  dtp  = (float*)p;               p += (size_t)NH * NN * 4;        // 128 KiB

  dim3 g1(NN / 64, NH);
  gat_k1<<<g1, 256, 0, stream>>>(graph, W, a, ltgB, st, dtp);
  dim3 g2(NN / 64, NH);
  gat_k2<<<g2, 256, 0, stream>>>(ltgB, st, dtp, outp);
}